// Round 1
// baseline (7688.558 us; speedup 1.0000x reference)
//
#include <hip/hip_runtime.h>

// XSimGCL / LightGCN propagation: 3 × COO-SpMM + running sum, /4 at end.
// Inputs: user_emb [100000,64] f32, item_emb [50000,64] f32,
//         rows [3M] i32, cols [3M] i32, vals [3M] f32.
// Output: f32 [150000,64] (users then items, concatenated).

constexpr int N_USERS = 100000;
constexpr int N_ITEMS = 50000;
constexpr int N_NODES = N_USERS + N_ITEMS;
constexpr int EMB = 64;
constexpr int NNZ = 3000000;

// x0 = concat(user, item); acc = x0
__global__ void init_kernel(const float4* __restrict__ user,
                            const float4* __restrict__ item,
                            float4* __restrict__ x0,
                            float4* __restrict__ acc) {
    const int total = N_NODES * (EMB / 4);
    const int uelems = N_USERS * (EMB / 4);
    for (int i = blockIdx.x * blockDim.x + threadIdx.x; i < total;
         i += gridDim.x * blockDim.x) {
        float4 v = (i < uelems) ? user[i] : item[i - uelems];
        x0[i]  = v;
        acc[i] = v;
    }
}

__global__ void zero_kernel(float4* __restrict__ p, int n4) {
    const float4 z = make_float4(0.f, 0.f, 0.f, 0.f);
    for (int i = blockIdx.x * blockDim.x + threadIdx.x; i < n4;
         i += gridDim.x * blockDim.x) p[i] = z;
}

// 16 lanes per edge; lane d4 handles dims [4*d4, 4*d4+4).
// Gather x[col] (256B contiguous per edge), scatter-add into xout[row].
__global__ void spmm_kernel(const int* __restrict__ rows,
                            const int* __restrict__ cols,
                            const float* __restrict__ vals,
                            const float4* __restrict__ xin,
                            float* __restrict__ xout) {
    const long long total = (long long)NNZ * 16;
    for (long long t = (long long)blockIdx.x * blockDim.x + threadIdx.x; t < total;
         t += (long long)gridDim.x * blockDim.x) {
        const int e  = (int)(t >> 4);
        const int d4 = (int)(t & 15);
        const int c = cols[e];
        const int r = rows[e];
        const float v = vals[e];
        float4 xv = xin[c * (EMB / 4) + d4];
        float* o = xout + r * EMB + d4 * 4;
        atomicAdd(o + 0, v * xv.x);
        atomicAdd(o + 1, v * xv.y);
        atomicAdd(o + 2, v * xv.z);
        atomicAdd(o + 3, v * xv.w);
    }
}

// acc = (acc + x) * scale
__global__ void add_scale_kernel(float4* __restrict__ acc,
                                 const float4* __restrict__ x,
                                 float scale, int n4) {
    for (int i = blockIdx.x * blockDim.x + threadIdx.x; i < n4;
         i += gridDim.x * blockDim.x) {
        float4 a = acc[i];
        float4 b = x[i];
        a.x = (a.x + b.x) * scale;
        a.y = (a.y + b.y) * scale;
        a.z = (a.z + b.z) * scale;
        a.w = (a.w + b.w) * scale;
        acc[i] = a;
    }
}

extern "C" void kernel_launch(void* const* d_in, const int* in_sizes, int n_in,
                              void* d_out, int out_size, void* d_ws, size_t ws_size,
                              hipStream_t stream) {
    const float4* user = (const float4*)d_in[0];
    const float4* item = (const float4*)d_in[1];
    const int*   rows = (const int*)d_in[2];
    const int*   cols = (const int*)d_in[3];
    const float* vals = (const float*)d_in[4];
    float* out = (float*)d_out;

    float* ws0 = (float*)d_ws;                          // 38.4 MB
    float* ws1 = ws0 + (size_t)N_NODES * EMB;           // 38.4 MB

    const int n4 = N_NODES * (EMB / 4);                 // 2.4M float4
    const int BLK = 256;
    const int GRID_EW = 2048;                           // grid-stride elementwise
    const int GRID_SPMM = 4096;                         // grid-stride edges

    init_kernel<<<GRID_EW, BLK, 0, stream>>>(user, item, (float4*)ws0, (float4*)out);

    float* xc = ws0;
    float* xn = ws1;
    for (int layer = 0; layer < 3; ++layer) {
        zero_kernel<<<GRID_EW, BLK, 0, stream>>>((float4*)xn, n4);
        spmm_kernel<<<GRID_SPMM, BLK, 0, stream>>>(rows, cols, vals, (const float4*)xc, xn);
        const float scale = (layer == 2) ? 0.25f : 1.0f;
        add_scale_kernel<<<GRID_EW, BLK, 0, stream>>>((float4*)out, (const float4*)xn, scale, n4);
        float* tmp = xc; xc = xn; xn = tmp;
    }
}

// Round 2
// 773.709 us; speedup vs baseline: 9.9373x; 9.9373x over previous
//
#include <hip/hip_runtime.h>

// XSimGCL / LightGCN propagation: 3 x COO-SpMM + running sum, /4 at end.
// Round 2: replace scatter-atomic SpMM with on-device counting-sort to CSR
// (by destination row), then gather-style SpMM: 1 wave per row, 1 lane per dim,
// no atomics in the hot loop, one coalesced 256B store per row.

constexpr int N_USERS = 100000;
constexpr int N_ITEMS = 50000;
constexpr int N_NODES = N_USERS + N_ITEMS;
constexpr int EMB = 64;
constexpr int NNZ = 3000000;
constexpr int SCAN_BLK = 1024;
constexpr int N_SCAN_BLOCKS = (N_NODES + SCAN_BLK - 1) / SCAN_BLK;  // 147

// ---------------- build phase ----------------

__global__ void zero_int_kernel(int* __restrict__ p, int n) {
    for (int i = blockIdx.x * blockDim.x + threadIdx.x; i < n;
         i += gridDim.x * blockDim.x) p[i] = 0;
}

__global__ void histogram_kernel(const int* __restrict__ rows, int* __restrict__ counts) {
    for (int e = blockIdx.x * blockDim.x + threadIdx.x; e < NNZ;
         e += gridDim.x * blockDim.x)
        atomicAdd(&counts[rows[e]], 1);
}

// per-block exclusive scan (Hillis-Steele in LDS), emit block totals
__global__ void scan_blocks_kernel(const int* __restrict__ counts,
                                   int* __restrict__ scanned,
                                   int* __restrict__ bsums, int n) {
    __shared__ int sdata[SCAN_BLK];
    const int tid = threadIdx.x;
    const int gid = blockIdx.x * SCAN_BLK + tid;
    int v = (gid < n) ? counts[gid] : 0;
    sdata[tid] = v;
    __syncthreads();
    for (int off = 1; off < SCAN_BLK; off <<= 1) {
        int t = (tid >= off) ? sdata[tid - off] : 0;
        __syncthreads();
        sdata[tid] += t;
        __syncthreads();
    }
    if (gid < n) scanned[gid] = sdata[tid] - v;   // exclusive
    if (tid == SCAN_BLK - 1) bsums[blockIdx.x] = sdata[tid];
}

// single-block exclusive scan of the (<=256) block sums, in place
__global__ void scan_tops_kernel(int* __restrict__ bsums, int nb) {
    __shared__ int sdata[256];
    const int tid = threadIdx.x;
    int v = (tid < nb) ? bsums[tid] : 0;
    sdata[tid] = v;
    __syncthreads();
    for (int off = 1; off < 256; off <<= 1) {
        int t = (tid >= off) ? sdata[tid - off] : 0;
        __syncthreads();
        sdata[tid] += t;
        __syncthreads();
    }
    if (tid < nb) bsums[tid] = sdata[tid] - v;    // exclusive
}

// add block offsets -> row_start; also init cursor copy for the sort scatter
__global__ void scan_add_kernel(int* __restrict__ scanned,
                                const int* __restrict__ bsums,
                                int* __restrict__ cursor, int n) {
    const int gid = blockIdx.x * SCAN_BLK + threadIdx.x;
    if (gid < n) {
        int v = scanned[gid] + bsums[gid >> 10];
        scanned[gid] = v;
        cursor[gid]  = v;
    }
}

// counting-sort scatter: edges grouped by destination row, payload (col, val)
__global__ void scatter_edges_kernel(const int* __restrict__ rows,
                                     const int* __restrict__ cols,
                                     const float* __restrict__ vals,
                                     int* __restrict__ cursor,
                                     int2* __restrict__ edges) {
    for (int e = blockIdx.x * blockDim.x + threadIdx.x; e < NNZ;
         e += gridDim.x * blockDim.x) {
        int idx = atomicAdd(&cursor[rows[e]], 1);
        edges[idx] = make_int2(cols[e], __float_as_int(vals[e]));
    }
}

// ---------------- propagate phase ----------------

// x0 = concat(user, item); acc(d_out) = x0
__global__ void init_kernel(const float4* __restrict__ user,
                            const float4* __restrict__ item,
                            float4* __restrict__ x0,
                            float4* __restrict__ acc) {
    const int total = N_NODES * (EMB / 4);
    const int uelems = N_USERS * (EMB / 4);
    for (int i = blockIdx.x * blockDim.x + threadIdx.x; i < total;
         i += gridDim.x * blockDim.x) {
        float4 v = (i < uelems) ? user[i] : item[i - uelems];
        x0[i]  = v;
        acc[i] = v;
    }
}

// 1 wave per row, lane = dim. xout[r] = sum_e val*xin[col];
// acc = (acc + xout) * scale   (scale=1 except last layer 0.25)
__global__ void spmm_csr_kernel(const int* __restrict__ row_start,
                                const int* __restrict__ counts,
                                const int2* __restrict__ edges,
                                const float* __restrict__ xin,
                                float* __restrict__ xout,
                                float* __restrict__ acc,
                                float scale) {
    const int lane = threadIdx.x & 63;
    const int wid  = (blockIdx.x * blockDim.x + threadIdx.x) >> 6;
    const int nw   = (gridDim.x * blockDim.x) >> 6;
    for (int r = wid; r < N_NODES; r += nw) {
        const int s = row_start[r];
        const int n = counts[r];
        float a0 = 0.f, a1 = 0.f, a2 = 0.f, a3 = 0.f;
        int j = 0;
        for (; j + 4 <= n; j += 4) {
            int2 e0 = edges[s + j + 0];
            int2 e1 = edges[s + j + 1];
            int2 e2 = edges[s + j + 2];
            int2 e3 = edges[s + j + 3];
            a0 += __int_as_float(e0.y) * xin[(size_t)e0.x * EMB + lane];
            a1 += __int_as_float(e1.y) * xin[(size_t)e1.x * EMB + lane];
            a2 += __int_as_float(e2.y) * xin[(size_t)e2.x * EMB + lane];
            a3 += __int_as_float(e3.y) * xin[(size_t)e3.x * EMB + lane];
        }
        for (; j < n; ++j) {
            int2 e = edges[s + j];
            a0 += __int_as_float(e.y) * xin[(size_t)e.x * EMB + lane];
        }
        const float a = (a0 + a1) + (a2 + a3);
        const size_t o = (size_t)r * EMB + lane;
        xout[o] = a;
        acc[o]  = (acc[o] + a) * scale;
    }
}

extern "C" void kernel_launch(void* const* d_in, const int* in_sizes, int n_in,
                              void* d_out, int out_size, void* d_ws, size_t ws_size,
                              hipStream_t stream) {
    const float4* user = (const float4*)d_in[0];
    const float4* item = (const float4*)d_in[1];
    const int*   rows = (const int*)d_in[2];
    const int*   cols = (const int*)d_in[3];
    const float* vals = (const float*)d_in[4];
    float* out = (float*)d_out;

    // workspace layout (~103 MB)
    char* w = (char*)d_ws;
    float* x0 = (float*)w;                         w += (size_t)N_NODES * EMB * 4;  // 38.4 MB
    float* x1 = (float*)w;                         w += (size_t)N_NODES * EMB * 4;  // 38.4 MB
    int2* edges = (int2*)w;                        w += (size_t)NNZ * 8;            // 24 MB
    int* counts    = (int*)w;                      w += (size_t)N_NODES * 4;
    int* row_start = (int*)w;                      w += (size_t)N_NODES * 4;
    int* cursor    = (int*)w;                      w += (size_t)N_NODES * 4;
    int* bsums     = (int*)w;                      w += 256 * 4;

    const int BLK = 256;
    const int GRID = 2048;

    // ---- build CSR-by-row (counting sort), once per call ----
    zero_int_kernel<<<256, BLK, 0, stream>>>(counts, N_NODES);
    histogram_kernel<<<GRID, BLK, 0, stream>>>(rows, counts);
    scan_blocks_kernel<<<N_SCAN_BLOCKS, SCAN_BLK, 0, stream>>>(counts, row_start, bsums, N_NODES);
    scan_tops_kernel<<<1, 256, 0, stream>>>(bsums, N_SCAN_BLOCKS);
    scan_add_kernel<<<N_SCAN_BLOCKS, SCAN_BLK, 0, stream>>>(row_start, bsums, cursor, N_NODES);
    scatter_edges_kernel<<<GRID, BLK, 0, stream>>>(rows, cols, vals, cursor, edges);

    // ---- init + 3 propagation layers ----
    init_kernel<<<GRID, BLK, 0, stream>>>(user, item, (float4*)x0, (float4*)out);

    float* xc = x0;
    float* xn = x1;
    for (int layer = 0; layer < 3; ++layer) {
        const float scale = (layer == 2) ? 0.25f : 1.0f;
        spmm_csr_kernel<<<GRID, BLK, 0, stream>>>(row_start, counts, edges,
                                                  xc, xn, out, scale);
        float* tmp = xc; xc = xn; xn = tmp;
    }
}